// Round 2
// baseline (733.266 us; speedup 1.0000x reference)
//
#include <hip/hip_runtime.h>
#include <math.h>

#define KNBR 64
#define DHALF 500
#define TWO_D 1000
#define ATTN_DIM 128
#define ETA_MAX 0.5f

// ===========================================================================
// Kernel 1: cos/sin tables of rel_phase, padded to 512 cols (zeros) so the
// refine kernel can do unguarded float4 loads. ~120K precise sincos, ~2 us.
// ===========================================================================
__global__ __launch_bounds__(256) void build_tables(
    const float* __restrict__ P, float* __restrict__ ctab,
    float* __restrict__ stab, int R)
{
    int idx = blockIdx.x * 256 + threadIdx.x;
    if (idx >= R * 512) return;
    int r = idx >> 9, d = idx & 511;
    float c = 0.f, s = 0.f;
    if (d < DHALF) { float ph = P[r * DHALF + d]; sincosf(ph, &s, &c); }
    ctab[idx] = c;
    stab[idx] = s;
}

// ===========================================================================
// Kernel 2: G2 = (Wq^T Wk) / sqrt(ATTN), stored [1000][1024-stride] (pad cols
// zeroed). logits = e_b^T G2 hat. 64x64 tiles, K=128 staged fully in LDS,
// everything coalesced. 256 blocks.
// ===========================================================================
__global__ __launch_bounds__(256) void build_g2(
    const float* __restrict__ Wq, const float* __restrict__ Wk,
    float* __restrict__ G2)
{
    __shared__ float At[ATTN_DIM][64];  // 32 KB
    __shared__ float Bt[ATTN_DIM][64];  // 32 KB
    const int t = threadIdx.x;
    const int d1_0 = blockIdx.y * 64, d2_0 = blockIdx.x * 64;
#pragma unroll
    for (int i = 0; i < 32; ++i) {
        int idx = t + 256 * i;
        int a = idx >> 6, c = idx & 63;
        int d1 = d1_0 + c, d2 = d2_0 + c;
        At[a][c] = (d1 < TWO_D) ? Wq[(size_t)a * TWO_D + d1] : 0.f;
        Bt[a][c] = (d2 < TWO_D) ? Wk[(size_t)a * TWO_D + d2] : 0.f;
    }
    __syncthreads();
    const int tx = t & 15, ty = t >> 4;
    float acc[4][4] = {};
    for (int a = 0; a < ATTN_DIM; ++a) {
        float av[4], bv[4];
#pragma unroll
        for (int i = 0; i < 4; ++i) av[i] = At[a][4 * ty + i];
#pragma unroll
        for (int j = 0; j < 4; ++j) bv[j] = Bt[a][4 * tx + j];
#pragma unroll
        for (int i = 0; i < 4; ++i)
#pragma unroll
            for (int j = 0; j < 4; ++j) acc[i][j] += av[i] * bv[j];
    }
    const float inv_scale = 0.0883883476483184f;  // 1/sqrt(128)
#pragma unroll
    for (int i = 0; i < 4; ++i) {
        int d1 = d1_0 + 4 * ty + i;
        if (d1 < TWO_D) {
#pragma unroll
            for (int j = 0; j < 4; ++j) {
                int d2 = d2_0 + 4 * tx + j;
                G2[(size_t)d1 * 1024 + d2] = acc[i][j] * inv_scale;  // pad cols = 0
            }
        }
    }
}

// ===========================================================================
// Kernel 3: M[b,:] = e_{anchor(b)}^T G2. Standard 64x64-tile fp32 GEMM,
// K=1000 in 32-chunks, all staging coalesced, +1 pad kills bank conflicts.
// 256 blocks (vs the old 128-block column-strided kernel).
// ===========================================================================
__global__ __launch_bounds__(256) void gemm_M(
    const int* __restrict__ anchor_ids, const float* __restrict__ E,
    const float* __restrict__ G2, float* __restrict__ M, int B)
{
    __shared__ float At[64][33];  // [anchor-row][k] padded
    __shared__ float Bt[32][64];  // [k][d2]
    __shared__ int rows_s[64];
    const int t = threadIdx.x;
    const int bx = blockIdx.x, by = blockIdx.y;
    if (t < 64) { int bb = by * 64 + t; rows_s[t] = (bb < B) ? anchor_ids[bb] : 0; }
    __syncthreads();
    const int tx = t & 15, ty = t >> 4;
    float acc[4][4] = {};
    for (int k0 = 0; k0 < TWO_D; k0 += 32) {
#pragma unroll
        for (int i = 0; i < 8; ++i) {
            int idx = t + 256 * i;
            int r = idx >> 5, c = idx & 31;
            int k = k0 + c;
            At[r][c] = (k < TWO_D) ? E[(size_t)rows_s[r] * TWO_D + k] : 0.f;
        }
#pragma unroll
        for (int i = 0; i < 8; ++i) {
            int idx = t + 256 * i;
            int r = idx >> 6, c = idx & 63;
            int k = k0 + r;
            Bt[r][c] = (k < TWO_D) ? G2[(size_t)k * 1024 + bx * 64 + c] : 0.f;
        }
        __syncthreads();
#pragma unroll
        for (int kk = 0; kk < 32; ++kk) {
            float av[4], bv[4];
#pragma unroll
            for (int i = 0; i < 4; ++i) av[i] = At[4 * ty + i][kk];
#pragma unroll
            for (int j = 0; j < 4; ++j) bv[j] = Bt[kk][4 * tx + j];
#pragma unroll
            for (int i = 0; i < 4; ++i)
#pragma unroll
                for (int j = 0; j < 4; ++j) acc[i][j] += av[i] * bv[j];
        }
        __syncthreads();
    }
#pragma unroll
    for (int i = 0; i < 4; ++i) {
        int b = by * 64 + 4 * ty + i;
        if (b < B) {
#pragma unroll
            for (int j = 0; j < 4; ++j) {
                int d2 = bx * 64 + 4 * tx + j;
                if (d2 < TWO_D) M[(size_t)b * TWO_D + d2] = acc[i][j];
            }
        }
    }
}

// ===========================================================================
// Kernel 4: refine. One block per anchor, 4 waves, ballot-compacted active
// neighbor list, float4 loads (8 VMEM/neighbor), table-lookup rotation,
// depth-2 software pipeline (next neighbor's loads fly over the current
// shfl+exp chain). Max-free softmax (|logit| ~ 0.1).
// ===========================================================================
struct NbrData {
    float4 re0, re1, im0, im1, c0, c1, s0, s1;
    float rb, ds;
};

__device__ __forceinline__ void load_nbr(
    int j, int lane, const float* __restrict__ E,
    const float* __restrict__ ctab, const float* __restrict__ stab,
    const int* ent_s, const int* rel_s, const float* rb_s, const float* ds_s,
    NbrData& n)
{
    const int ent = ent_s[j];
    const int rel = rel_s[j];
    const float4* er = (const float4*)(E + (size_t)ent * TWO_D);
    const float4* cr = (const float4*)(ctab + (size_t)rel * 512);
    const float4* sr = (const float4*)(stab + (size_t)rel * 512);
    n.re0 = er[lane];          // dims 4l .. 4l+3        (0..255)
    n.im0 = er[125 + lane];    // dims 500+4l            (500..755)
    n.re1 = make_float4(0.f, 0.f, 0.f, 0.f);
    n.im1 = make_float4(0.f, 0.f, 0.f, 0.f);
    if (lane < 61) {           // dims 256+4l (<500) / 756+4l (<1000)
        n.re1 = er[64 + lane];
        n.im1 = er[189 + lane];
    }
    n.c0 = cr[lane];      n.c1 = cr[64 + lane];   // pad cols are zero
    n.s0 = sr[lane];      n.s1 = sr[64 + lane];
    n.rb = rb_s[j];
    n.ds = ds_s[j];
}

__device__ __forceinline__ void compute_nbr(
    const NbrData& n,
    const float4& mre0, const float4& mre1, const float4& mim0, const float4& mim1,
    float4& are0, float4& are1, float4& aim0, float4& aim1, float& wsum)
{
    const float ds = n.ds;
    float4 hre0, hre1, him0, him1;
    float dot = 0.f;
#define ROT_DOT(F)                                                              \
    {                                                                           \
        float se0 = n.s0.F * ds;                                                \
        hre0.F = n.re0.F * n.c0.F - n.im0.F * se0;                              \
        him0.F = n.re0.F * se0 + n.im0.F * n.c0.F;                              \
        dot += mre0.F * hre0.F + mim0.F * him0.F;                               \
        float se1 = n.s1.F * ds;                                                \
        hre1.F = n.re1.F * n.c1.F - n.im1.F * se1;                              \
        him1.F = n.re1.F * se1 + n.im1.F * n.c1.F;                              \
        dot += mre1.F * hre1.F + mim1.F * him1.F;                               \
    }
    ROT_DOT(x) ROT_DOT(y) ROT_DOT(z) ROT_DOT(w)
#undef ROT_DOT
    dot += __shfl_xor(dot, 32);
    dot += __shfl_xor(dot, 16);
    dot += __shfl_xor(dot, 8);
    dot += __shfl_xor(dot, 4);
    dot += __shfl_xor(dot, 2);
    dot += __shfl_xor(dot, 1);
    const float p = __expf(dot + n.rb);
    wsum += p;
#define ACC(F)                                                                  \
    are0.F += p * hre0.F; are1.F += p * hre1.F;                                 \
    aim0.F += p * him0.F; aim1.F += p * him1.F;
    ACC(x) ACC(y) ACC(z) ACC(w)
#undef ACC
}

__global__ __launch_bounds__(256) void refine(
    const int* __restrict__ anchor_ids,
    const int* __restrict__ nbr_ent,
    const int* __restrict__ nbr_rel,
    const int* __restrict__ nbr_dir,
    const int* __restrict__ nbr_mask,
    const float* __restrict__ freq,
    const float* __restrict__ E,
    const float* __restrict__ ctab,
    const float* __restrict__ stab,
    const float* __restrict__ a_param,
    const float* __restrict__ eta_raw_p,
    const float* __restrict__ w_raw_p,
    const float* __restrict__ b_p,
    const float* __restrict__ rel_bias,
    const float* __restrict__ dir_bias,
    const float* __restrict__ M,
    float* __restrict__ out)
{
    __shared__ float accm[4][TWO_D];  // 16 KB merge
    __shared__ float sum_s[4];
    __shared__ int ent_s[KNBR], rel_s[KNBR];
    __shared__ float rb_s[KNBR], ds_s[KNBR];
    __shared__ int act_n_s;

    const int t = threadIdx.x;
    const int bid = blockIdx.x;
    const int lane = t & 63;
    const int wid = t >> 6;
    const int anchor = anchor_ids[bid];

    // wave 0: ballot-compact the active neighbor list + fold biases
    if (wid == 0) {
        size_t off = (size_t)anchor * KNBR + lane;
        int msk = nbr_mask[off];
        unsigned long long bal = __ballot(msk != 0);
        if (msk) {
            int rank = __popcll(bal & ((1ull << lane) - 1ull));
            int rel = nbr_rel[off];
            int dirf = nbr_dir[off];
            ent_s[rank] = nbr_ent[off];
            rel_s[rank] = rel;
            ds_s[rank] = dirf ? -1.f : 1.f;
            rb_s[rank] = rel_bias[rel] + dir_bias[dirf ? 1 : 0];
        }
        if (lane == 0) act_n_s = (int)__popcll(bal);
    }
    __syncthreads();
    const int an = act_n_s;

    // per-lane slice of M row (same float4 layout as E rows)
    const float4* mr = (const float4*)(M + (size_t)bid * TWO_D);
    float4 mre0 = mr[lane];
    float4 mim0 = mr[125 + lane];
    float4 mre1 = make_float4(0.f, 0.f, 0.f, 0.f);
    float4 mim1 = make_float4(0.f, 0.f, 0.f, 0.f);
    if (lane < 61) { mre1 = mr[64 + lane]; mim1 = mr[189 + lane]; }

    float4 are0 = make_float4(0.f, 0.f, 0.f, 0.f), are1 = are0, aim0 = are0, aim1 = are0;
    float wsum = 0.f;

    // depth-2 pipelined sweep over this wave's items: j = wid, wid+4, ...
    NbrData cur, nxt;
    int j = wid;
    bool have = (j < an);
    if (have) load_nbr(j, lane, E, ctab, stab, ent_s, rel_s, rb_s, ds_s, cur);
    while (have) {
        int jn = j + 4;
        bool haveN = (jn < an);
        if (haveN) load_nbr(jn, lane, E, ctab, stab, ent_s, rel_s, rb_s, ds_s, nxt);
        compute_nbr(cur, mre0, mre1, mim0, mim1, are0, are1, aim0, aim1, wsum);
        cur = nxt;
        j = jn;
        have = haveN;
    }

    if (lane == 0) sum_s[wid] = wsum;
    {
        float4* am = (float4*)(&accm[wid][0]);
        am[lane] = are0;
        am[125 + lane] = aim0;
        if (lane < 61) { am[64 + lane] = are1; am[189 + lane] = aim1; }
    }
    __syncthreads();

    const float S = sum_s[0] + sum_s[1] + sum_s[2] + sum_s[3];
    const float invS = (S > 0.f) ? 1.f / S : 0.f;
    float eta = 0.f;
    if (S > 0.f) {
        float logf_ = log1pf(freq[anchor]);
        float wv = log1pf(__expf(w_raw_p[0]));  // softplus
        float x = eta_raw_p[0] - wv * logf_ + b_p[0];
        eta = ETA_MAX / (1.f + __expf(-x));
    }

    const float* eirow = E + (size_t)anchor * TWO_D;
#pragma unroll
    for (int c = 0; c < 4; ++c) {
        int dd = t + 256 * c;
        if (dd < TWO_D) {
            float delta = (accm[0][dd] + accm[1][dd] + accm[2][dd] + accm[3][dd]) * invS;
            float ei = eirow[dd];
            float ap = a_param[(dd < DHALF) ? dd : dd - DHALF];
            out[(size_t)bid * TWO_D + dd] = ei + eta * (ap * delta - ei);
        }
    }
}

// ===========================================================================
extern "C" void kernel_launch(void* const* d_in, const int* in_sizes, int n_in,
                              void* d_out, int out_size, void* d_ws, size_t ws_size,
                              hipStream_t stream)
{
    const int*   anchor_ids = (const int*)d_in[0];
    const int*   nbr_ent    = (const int*)d_in[1];
    const int*   nbr_rel    = (const int*)d_in[2];
    const int*   nbr_dir    = (const int*)d_in[3];
    const int*   nbr_mask   = (const int*)d_in[4];
    const float* freq       = (const float*)d_in[5];
    const float* E          = (const float*)d_in[6];
    const float* P          = (const float*)d_in[7];
    const float* a_param    = (const float*)d_in[8];
    const float* eta_raw    = (const float*)d_in[9];
    const float* w_raw      = (const float*)d_in[10];
    const float* b_scalar   = (const float*)d_in[11];
    const float* Wq         = (const float*)d_in[12];
    const float* Wk         = (const float*)d_in[13];
    const float* rel_bias   = (const float*)d_in[14];
    const float* dir_bias   = (const float*)d_in[15];
    float* out = (float*)d_out;

    const int B = in_sizes[0];
    const int R = in_sizes[7] / DHALF;  // rel_phase is [R, DHALF]

    auto align256 = [](size_t x) { return (x + 255) & ~(size_t)255; };
    char* ws = (char*)d_ws;
    size_t offM  = 0;
    size_t offG2 = align256(offM + (size_t)B * TWO_D * 4);
    size_t offC  = align256(offG2 + (size_t)TWO_D * 1024 * 4);
    size_t offS  = align256(offC + (size_t)R * 512 * 4);
    float* M    = (float*)(ws + offM);
    float* G2   = (float*)(ws + offG2);
    float* ctab = (float*)(ws + offC);
    float* stab = (float*)(ws + offS);

    build_tables<<<(R * 512 + 255) / 256, 256, 0, stream>>>(P, ctab, stab, R);
    build_g2<<<dim3(16, 16), 256, 0, stream>>>(Wq, Wk, G2);
    gemm_M<<<dim3(16, (B + 63) / 64), 256, 0, stream>>>(anchor_ids, E, G2, M, B);
    refine<<<B, 256, 0, stream>>>(anchor_ids, nbr_ent, nbr_rel, nbr_dir, nbr_mask,
                                  freq, E, ctab, stab, a_param, eta_raw, w_raw,
                                  b_scalar, rel_bias, dir_bias, M, out);
}

// Round 3
// 731.931 us; speedup vs baseline: 1.0018x; 1.0018x over previous
//
#include <hip/hip_runtime.h>
#include <math.h>

#define KNBR 64
#define DHALF 500
#define TWO_D 1000
#define ATTN_DIM 128
#define ETA_MAX 0.5f

// ===========================================================================
// Kernel 1: cos/sin tables of rel_phase, padded to 512 cols (zeros) so the
// refine kernel can do unguarded float4 loads. ~120K precise sincos, ~2 us.
// ===========================================================================
__global__ __launch_bounds__(256) void build_tables(
    const float* __restrict__ P, float* __restrict__ ctab,
    float* __restrict__ stab, int R)
{
    int idx = blockIdx.x * 256 + threadIdx.x;
    if (idx >= R * 512) return;
    int r = idx >> 9, d = idx & 511;
    float c = 0.f, s = 0.f;
    if (d < DHALF) { float ph = P[r * DHALF + d]; sincosf(ph, &s, &c); }
    ctab[idx] = c;
    stab[idx] = s;
}

// ===========================================================================
// Kernel 2: G2 = (Wq^T Wk) / sqrt(ATTN), stored [1000][1024-stride] (pad cols
// zeroed). logits = e_b^T G2 hat. 64x64 tiles, K=128 staged fully in LDS.
// ===========================================================================
__global__ __launch_bounds__(256) void build_g2(
    const float* __restrict__ Wq, const float* __restrict__ Wk,
    float* __restrict__ G2)
{
    __shared__ float At[ATTN_DIM][64];  // 32 KB
    __shared__ float Bt[ATTN_DIM][64];  // 32 KB
    const int t = threadIdx.x;
    const int d1_0 = blockIdx.y * 64, d2_0 = blockIdx.x * 64;
#pragma unroll
    for (int i = 0; i < 32; ++i) {
        int idx = t + 256 * i;
        int a = idx >> 6, c = idx & 63;
        int d1 = d1_0 + c, d2 = d2_0 + c;
        At[a][c] = (d1 < TWO_D) ? Wq[(size_t)a * TWO_D + d1] : 0.f;
        Bt[a][c] = (d2 < TWO_D) ? Wk[(size_t)a * TWO_D + d2] : 0.f;
    }
    __syncthreads();
    const int tx = t & 15, ty = t >> 4;
    float acc[4][4] = {};
    for (int a = 0; a < ATTN_DIM; ++a) {
        float av[4], bv[4];
#pragma unroll
        for (int i = 0; i < 4; ++i) av[i] = At[a][4 * ty + i];
#pragma unroll
        for (int j = 0; j < 4; ++j) bv[j] = Bt[a][4 * tx + j];
#pragma unroll
        for (int i = 0; i < 4; ++i)
#pragma unroll
            for (int j = 0; j < 4; ++j) acc[i][j] += av[i] * bv[j];
    }
    const float inv_scale = 0.0883883476483184f;  // 1/sqrt(128)
#pragma unroll
    for (int i = 0; i < 4; ++i) {
        int d1 = d1_0 + 4 * ty + i;
        if (d1 < TWO_D) {
#pragma unroll
            for (int j = 0; j < 4; ++j) {
                int d2 = d2_0 + 4 * tx + j;
                G2[(size_t)d1 * 1024 + d2] = acc[i][j] * inv_scale;  // pad = 0
            }
        }
    }
}

// ===========================================================================
// Kernel 3: M[b,:] = e_{anchor(b)}^T G2. 64x64 tiles, K in 32-chunks.
// A-tile stored k-major (At_k[kk][r], stride 65: conflict-free staging,
// 2-way-free b128 inner reads) so BOTH inner operands are ds_read_b128:
// 2 b128 + 16 FMA per kk -> VALU-bound (~14 us floor at 157 TF).
// ===========================================================================
__global__ __launch_bounds__(256) void gemm_M(
    const int* __restrict__ anchor_ids, const float* __restrict__ E,
    const float* __restrict__ G2, float* __restrict__ M, int B)
{
    __shared__ float At_k[32][65];  // [k][anchor-row], pad 65
    __shared__ float Bt[32][64];    // [k][d2]
    __shared__ int rows_s[64];
    const int t = threadIdx.x;
    const int bx = blockIdx.x, by = blockIdx.y;
    if (t < 64) { int bb = by * 64 + t; rows_s[t] = (bb < B) ? anchor_ids[bb] : 0; }
    __syncthreads();
    const int tx = t & 15, ty = t >> 4;
    float acc[4][4] = {};
    for (int k0 = 0; k0 < TWO_D; k0 += 32) {
#pragma unroll
        for (int i = 0; i < 8; ++i) {
            int idx = t + 256 * i;
            int r = idx >> 5, c = idx & 31;   // r: anchor row, c: k within chunk
            int k = k0 + c;
            At_k[c][r] = (k < TWO_D) ? E[(size_t)rows_s[r] * TWO_D + k] : 0.f;
        }
#pragma unroll
        for (int i = 0; i < 8; ++i) {
            int idx = t + 256 * i;
            int r = idx >> 6, c = idx & 63;
            int k = k0 + r;
            Bt[r][c] = (k < TWO_D) ? G2[(size_t)k * 1024 + bx * 64 + c] : 0.f;
        }
        __syncthreads();
#pragma unroll
        for (int kk = 0; kk < 32; ++kk) {
            float4 av = *(const float4*)&At_k[kk][4 * ty];
            float4 bv = *(const float4*)&Bt[kk][4 * tx];
            const float a4[4] = {av.x, av.y, av.z, av.w};
            const float b4[4] = {bv.x, bv.y, bv.z, bv.w};
#pragma unroll
            for (int i = 0; i < 4; ++i)
#pragma unroll
                for (int j = 0; j < 4; ++j) acc[i][j] += a4[i] * b4[j];
        }
        __syncthreads();
    }
#pragma unroll
    for (int i = 0; i < 4; ++i) {
        int b = by * 64 + 4 * ty + i;
        if (b < B) {
#pragma unroll
            for (int j = 0; j < 4; ++j) {
                int d2 = bx * 64 + 4 * tx + j;
                if (d2 < TWO_D) M[(size_t)b * TWO_D + d2] = acc[i][j];
            }
        }
    }
}

// ===========================================================================
// Kernel 4: refine. One block/anchor, 4 waves. Register-lean design:
//   - depth-2 pipeline on the ENTITY row only (16 regs, not the full 34-reg
//     neighbor struct of R2 -> peak ~104 VGPR, 4 waves/EU enforced)
//   - cos/sin rows read at point of use (970 KB tables are L2-resident;
//     ~200cy latency covered by 4 waves/EU)
//   - ballot-compacted active list, max-free softmax (|logit| ~ 0.1)
// ===========================================================================
__global__ __launch_bounds__(256, 4) void refine(
    const int* __restrict__ anchor_ids,
    const int* __restrict__ nbr_ent,
    const int* __restrict__ nbr_rel,
    const int* __restrict__ nbr_dir,
    const int* __restrict__ nbr_mask,
    const float* __restrict__ freq,
    const float* __restrict__ E,
    const float* __restrict__ ctab,
    const float* __restrict__ stab,
    const float* __restrict__ a_param,
    const float* __restrict__ eta_raw_p,
    const float* __restrict__ w_raw_p,
    const float* __restrict__ b_p,
    const float* __restrict__ rel_bias,
    const float* __restrict__ dir_bias,
    const float* __restrict__ M,
    float* __restrict__ out)
{
    __shared__ float accm[4][TWO_D];  // 16 KB merge
    __shared__ float sum_s[4];
    __shared__ int ent_s[KNBR], rel_s[KNBR];
    __shared__ float rb_s[KNBR], ds_s[KNBR];
    __shared__ int act_n_s;

    const int t = threadIdx.x;
    const int bid = blockIdx.x;
    const int lane = t & 63;
    const int wid = t >> 6;
    const int anchor = anchor_ids[bid];

    // wave 0: ballot-compact active neighbors + fold biases
    if (wid == 0) {
        size_t off = (size_t)anchor * KNBR + lane;
        int msk = nbr_mask[off];
        unsigned long long bal = __ballot(msk != 0);
        if (msk) {
            int rank = __popcll(bal & ((1ull << lane) - 1ull));
            int rel = nbr_rel[off];
            int dirf = nbr_dir[off];
            ent_s[rank] = nbr_ent[off];
            rel_s[rank] = rel;
            ds_s[rank] = dirf ? -1.f : 1.f;
            rb_s[rank] = rel_bias[rel] + dir_bias[dirf ? 1 : 0];
        }
        if (lane == 0) act_n_s = (int)__popcll(bal);
    }

    // all waves: per-lane slice of M row (independent of compaction)
    const float4* mr = (const float4*)(M + (size_t)bid * TWO_D);
    float4 mre0 = mr[lane];
    float4 mim0 = mr[125 + lane];
    float4 mre1 = make_float4(0.f, 0.f, 0.f, 0.f), mim1 = mre1;
    if (lane < 61) { mre1 = mr[64 + lane]; mim1 = mr[189 + lane]; }

    __syncthreads();
    const int an = act_n_s;

    float4 are0 = make_float4(0.f, 0.f, 0.f, 0.f);
    float4 are1 = are0, aim0 = are0, aim1 = are0;
    float wsum = 0.f;

    // entity-row pipeline registers
    float4 ere0, ere1, eim0, eim1;  // current
    float4 nre0, nre1, nim0, nim1;  // next (prefetch)

    int j = wid;
    if (j < an) {
        const float4* er = (const float4*)(E + (size_t)ent_s[j] * TWO_D);
        ere0 = er[lane];
        eim0 = er[125 + lane];
        ere1 = make_float4(0.f, 0.f, 0.f, 0.f); eim1 = ere1;
        if (lane < 61) { ere1 = er[64 + lane]; eim1 = er[189 + lane]; }
    }
    for (; j < an; j += 4) {
        const int jn = j + 4;
        if (jn < an) {  // prefetch next entity row (HBM, flies over compute)
            const float4* er = (const float4*)(E + (size_t)ent_s[jn] * TWO_D);
            nre0 = er[lane];
            nim0 = er[125 + lane];
            nre1 = make_float4(0.f, 0.f, 0.f, 0.f); nim1 = nre1;
            if (lane < 61) { nre1 = er[64 + lane]; nim1 = er[189 + lane]; }
        }
        // tables for current neighbor (L2-hot)
        const int rel = rel_s[j];
        const float4* cr = (const float4*)(ctab + (size_t)rel * 512);
        const float4* sr = (const float4*)(stab + (size_t)rel * 512);
        const float4 c0 = cr[lane], c1 = cr[64 + lane];
        const float4 s0 = sr[lane], s1 = sr[64 + lane];
        const float dsg = ds_s[j];

        float4 hre0, hre1, him0, him1;
        float dot = 0.f;
#define ROT_DOT(F)                                                          \
        {                                                                   \
            float se0 = s0.F * dsg;                                         \
            hre0.F = ere0.F * c0.F - eim0.F * se0;                          \
            him0.F = ere0.F * se0 + eim0.F * c0.F;                          \
            dot += mre0.F * hre0.F + mim0.F * him0.F;                       \
            float se1 = s1.F * dsg;                                         \
            hre1.F = ere1.F * c1.F - eim1.F * se1;                          \
            him1.F = ere1.F * se1 + eim1.F * c1.F;                          \
            dot += mre1.F * hre1.F + mim1.F * him1.F;                       \
        }
        ROT_DOT(x) ROT_DOT(y) ROT_DOT(z) ROT_DOT(w)
#undef ROT_DOT
        dot += __shfl_xor(dot, 32);
        dot += __shfl_xor(dot, 16);
        dot += __shfl_xor(dot, 8);
        dot += __shfl_xor(dot, 4);
        dot += __shfl_xor(dot, 2);
        dot += __shfl_xor(dot, 1);
        const float p = __expf(dot + rb_s[j]);
        wsum += p;
#define ACC(F)                                                              \
        are0.F += p * hre0.F; are1.F += p * hre1.F;                         \
        aim0.F += p * him0.F; aim1.F += p * him1.F;
        ACC(x) ACC(y) ACC(z) ACC(w)
#undef ACC
        ere0 = nre0; ere1 = nre1; eim0 = nim0; eim1 = nim1;
    }

    if (lane == 0) sum_s[wid] = wsum;
    {
        float4* am = (float4*)(&accm[wid][0]);
        am[lane] = are0;
        am[125 + lane] = aim0;
        if (lane < 61) { am[64 + lane] = are1; am[189 + lane] = aim1; }
    }
    __syncthreads();

    const float S = sum_s[0] + sum_s[1] + sum_s[2] + sum_s[3];
    const float invS = (S > 0.f) ? 1.f / S : 0.f;
    float eta = 0.f;
    if (S > 0.f) {
        float logf_ = log1pf(freq[anchor]);
        float wv = log1pf(__expf(w_raw_p[0]));  // softplus
        float x = eta_raw_p[0] - wv * logf_ + b_p[0];
        eta = ETA_MAX / (1.f + __expf(-x));
    }

    const float* eirow = E + (size_t)anchor * TWO_D;
#pragma unroll
    for (int c = 0; c < 4; ++c) {
        int dd = t + 256 * c;
        if (dd < TWO_D) {
            float delta = (accm[0][dd] + accm[1][dd] + accm[2][dd] + accm[3][dd]) * invS;
            float ei = eirow[dd];
            float ap = a_param[(dd < DHALF) ? dd : dd - DHALF];
            out[(size_t)bid * TWO_D + dd] = ei + eta * (ap * delta - ei);
        }
    }
}

// ===========================================================================
extern "C" void kernel_launch(void* const* d_in, const int* in_sizes, int n_in,
                              void* d_out, int out_size, void* d_ws, size_t ws_size,
                              hipStream_t stream)
{
    const int*   anchor_ids = (const int*)d_in[0];
    const int*   nbr_ent    = (const int*)d_in[1];
    const int*   nbr_rel    = (const int*)d_in[2];
    const int*   nbr_dir    = (const int*)d_in[3];
    const int*   nbr_mask   = (const int*)d_in[4];
    const float* freq       = (const float*)d_in[5];
    const float* E          = (const float*)d_in[6];
    const float* P          = (const float*)d_in[7];
    const float* a_param    = (const float*)d_in[8];
    const float* eta_raw    = (const float*)d_in[9];
    const float* w_raw      = (const float*)d_in[10];
    const float* b_scalar   = (const float*)d_in[11];
    const float* Wq         = (const float*)d_in[12];
    const float* Wk         = (const float*)d_in[13];
    const float* rel_bias   = (const float*)d_in[14];
    const float* dir_bias   = (const float*)d_in[15];
    float* out = (float*)d_out;

    const int B = in_sizes[0];
    const int R = in_sizes[7] / DHALF;  // rel_phase is [R, DHALF]

    auto align256 = [](size_t x) { return (x + 255) & ~(size_t)255; };
    char* ws = (char*)d_ws;
    size_t offM  = 0;
    size_t offG2 = align256(offM + (size_t)B * TWO_D * 4);
    size_t offC  = align256(offG2 + (size_t)TWO_D * 1024 * 4);
    size_t offS  = align256(offC + (size_t)R * 512 * 4);
    float* M    = (float*)(ws + offM);
    float* G2   = (float*)(ws + offG2);
    float* ctab = (float*)(ws + offC);
    float* stab = (float*)(ws + offS);

    build_tables<<<(R * 512 + 255) / 256, 256, 0, stream>>>(P, ctab, stab, R);
    build_g2<<<dim3(16, 16), 256, 0, stream>>>(Wq, Wk, G2);
    gemm_M<<<dim3(16, (B + 63) / 64), 256, 0, stream>>>(anchor_ids, E, G2, M, B);
    refine<<<B, 256, 0, stream>>>(anchor_ids, nbr_ent, nbr_rel, nbr_dir, nbr_mask,
                                  freq, E, ctab, stab, a_param, eta_raw, w_raw,
                                  b_scalar, rel_bias, dir_bias, M, out);
}